// Round 6
// baseline (133.530 us; speedup 1.0000x reference)
//
#include <hip/hip_runtime.h>

// MultiHeadSelfAttention: N=8, C=512, heads=8, d=64, S=1024 (32x32), fp32 in/out.
// R17: BISECT round. R15/R16 ("Q-fusion + KV-split + vec-prep") killed the
// container twice (4 attempts) -> kernel implicated. This build = R14 verbatim
// (passed, 133.2us) with ONLY the vectorized prep swapped in. If this passes,
// prep is banked and the Q-fusion restructure is the confirmed killer (to be
// reintroduced in isolation next); if it fails, prep is the killer.

typedef _Float16 f16x8 __attribute__((ext_vector_type(8)));
typedef _Float16 f16x4 __attribute__((ext_vector_type(4)));
typedef float f32x4 __attribute__((ext_vector_type(4)));

__device__ inline void gl_lds16(const void* g, void* l) {
  __builtin_amdgcn_global_load_lds((const __attribute__((address_space(1))) void*)g,
                                   (__attribute__((address_space(3))) void*)l, 16, 0, 0);
}

__device__ inline float fexp2(float x) {
#if __has_builtin(__builtin_amdgcn_exp2f)
  return __builtin_amdgcn_exp2f(x);
#else
  return exp2f(x);
#endif
}

// ---------------- prep: weight cast (vec) + x transpose+cast (vec) -----------
// blocks [0,256): weights/bias. blocks [256,1280): x-part, 64c x 64s tiles,
// n = (bid-256)&7 -> XCD-pinned batch. (R15's vectorized prep — G13.)
__global__ void prep(const float* __restrict__ x,
                     const float* __restrict__ Wq, const float* __restrict__ bq,
                     const float* __restrict__ Wk, const float* __restrict__ bk,
                     const float* __restrict__ Wv, const float* __restrict__ bv,
                     const float* __restrict__ Wo,
                     _Float16* __restrict__ xs16, _Float16* __restrict__ Wqkv16,
                     float* __restrict__ bqkv, _Float16* __restrict__ Wo16) {
  const int tid = threadIdx.x;
  const int bid = blockIdx.x;
  const float g = 0.18033688011112042f;  // log2(e)/8
  if (bid < 256) {
    int i4 = (bid * 256 + tid) * 4;
    float4 q = *(const float4*)(Wq + i4);
    float4 k = *(const float4*)(Wk + i4);
    float4 v = *(const float4*)(Wv + i4);
    float4 o = *(const float4*)(Wo + i4);
    f16x4 qh = {(_Float16)(q.x * g), (_Float16)(q.y * g),
                (_Float16)(q.z * g), (_Float16)(q.w * g)};
    f16x4 kh = {(_Float16)k.x, (_Float16)k.y, (_Float16)k.z, (_Float16)k.w};
    f16x4 vh = {(_Float16)v.x, (_Float16)v.y, (_Float16)v.z, (_Float16)v.w};
    f16x4 oh = {(_Float16)o.x, (_Float16)o.y, (_Float16)o.z, (_Float16)o.w};
    *(f16x4*)(Wqkv16 + i4)          = qh;
    *(f16x4*)(Wqkv16 + 262144 + i4) = kh;
    *(f16x4*)(Wqkv16 + 524288 + i4) = vh;
    *(f16x4*)(Wo16 + i4)            = oh;
    if (bid == 0 && tid < 128) {
      int t4 = tid * 4;
      float4 b1 = *(const float4*)(bq + t4);
      float4 b2 = *(const float4*)(bk + t4);
      float4 b3 = *(const float4*)(bv + t4);
      b1.x *= g; b1.y *= g; b1.z *= g; b1.w *= g;
      *(float4*)(bqkv + t4)        = b1;
      *(float4*)(bqkv + 512 + t4)  = b2;
      *(float4*)(bqkv + 1024 + t4) = b3;
    }
    return;
  }
  __shared__ float t[64][65];
  const int bid2 = bid - 256;                   // 0..1023
  const int n = bid2 & 7;                       // XCD-pinned batch
  const int r7 = bid2 >> 3;                     // 0..127
  const int c0 = (r7 & 7) * 64, s0 = (r7 >> 3) * 64;
#pragma unroll
  for (int i = 0; i < 4; ++i) {
    int idx = i * 256 + tid;
    int rr = idx >> 4, cq = (idx & 15) * 4;     // rr = channel, cq = s offset
    float4 xv = *(const float4*)(x + (size_t)(n * 512 + c0 + rr) * 1024 + s0 + cq);
    t[rr][cq] = xv.x; t[rr][cq + 1] = xv.y; t[rr][cq + 2] = xv.z; t[rr][cq + 3] = xv.w;
  }
  __syncthreads();
#pragma unroll
  for (int i = 0; i < 2; ++i) {
    int idx = i * 256 + tid;
    int ss = idx >> 3, c8 = (idx & 7) * 8;      // ss = s offset, c8 = channel base
    f16x8 o;
#pragma unroll
    for (int kk = 0; kk < 8; ++kk) o[kk] = (_Float16)t[c8 + kk][ss];
    *(f16x8*)(xs16 + (size_t)(n * 1024 + s0 + ss) * 512 + c0 + c8) = o;
  }
}

// ---------------- QKV GEMM: (8192x512)*(1536x512)^T + bias, BK=64 ------------
// 1-D grid 768: xcd = id&7; k = id>>3; bm-tile = xcd*8 + (k&7) (batch = xcd);
// bn-tile = k>>3. Per-XCD: A 1MB + B 1.5MB fits 4MB L2.
// launch_bounds(256,3) -> 3 blocks/CU, grid 768 = exactly 3/CU, no tail.
__global__ __launch_bounds__(256, 3) void qkv_gemm(
    const _Float16* __restrict__ A, const _Float16* __restrict__ Bw,
    const float* __restrict__ bias, _Float16* __restrict__ QK,
    _Float16* __restrict__ Vt) {
  __shared__ _Float16 smem[16896];  // K-loop: As[0:8192) Bs[8192:16384); epi T 128x132
  _Float16* As = smem;
  _Float16* Bs = smem + 8192;
  const int tid = threadIdx.x;
  const int lane = tid & 63, w = tid >> 6;
  const int quad = lane >> 4, l15 = lane & 15;
  const int id = blockIdx.x;
  const int xcd = id & 7, k = id >> 3;
  const int bm = (xcd * 8 + (k & 7)) * 128;     // batch = xcd
  const int bnt = k >> 3;                       // 0..11
  const int bn = bnt * 128;
  const int wr = (w >> 1) * 64, wc = (w & 1) * 64;
  f32x4 acc[4][4] = {};
  for (int k0 = 0; k0 < 512; k0 += 64) {
    __syncthreads();
#pragma unroll
    for (int c = 0; c < 4; ++c) {
      int idx = c * 256 + tid;          // 0..1023
      int row = idx >> 3, sc = idx & 7;
      int kg = sc ^ (row & 7);          // XOR-chunk swizzle (8 chunks/row)
      gl_lds16(A + (size_t)(bm + row) * 512 + k0 + kg * 8, As + idx * 8);
      gl_lds16(Bw + (size_t)(bn + row) * 512 + k0 + kg * 8, Bs + idx * 8);
    }
    __syncthreads();
#pragma unroll
    for (int kh = 0; kh < 2; ++kh) {
      f16x8 af[4], bf[4];
#pragma unroll
      for (int i = 0; i < 4; ++i) {
        int ra = wr + i * 16 + l15;
        af[i] = *(const f16x8*)(As + ra * 64 + ((kh * 4 + quad) ^ (ra & 7)) * 8);
        int rb = wc + i * 16 + l15;
        bf[i] = *(const f16x8*)(Bs + rb * 64 + ((kh * 4 + quad) ^ (rb & 7)) * 8);
      }
#pragma unroll
      for (int i = 0; i < 4; ++i)
#pragma unroll
        for (int j = 0; j < 4; ++j)
          acc[i][j] = __builtin_amdgcn_mfma_f32_16x16x32_f16(af[i], bf[j], acc[i][j], 0, 0, 0);
    }
  }
  if (bnt < 8) {
    // Q/K blocks: direct store (lanes contiguous in col -> coalesced)
#pragma unroll
    for (int j = 0; j < 4; ++j) {
      int col = bn + wc + j * 16 + l15;
      float bb = bias[col];
#pragma unroll
      for (int i = 0; i < 4; ++i) {
        int rowb = bm + wr + i * 16 + quad * 4;
#pragma unroll
        for (int r = 0; r < 4; ++r)
          QK[(size_t)(rowb + r) * 1024 + col] = (_Float16)(acc[i][j][r] + bb);
      }
    }
  } else {
    // V blocks: transpose tile through LDS, store coalesced with s-permutation
    __syncthreads();  // As/Bs dead; reuse smem as T[col][row], stride 132
#pragma unroll
    for (int j = 0; j < 4; ++j) {
      int cl = wc + j * 16 + l15;
      float bb = bias[bn + cl];
#pragma unroll
      for (int i = 0; i < 4; ++i) {
        int row = wr + i * 16 + quad * 4;
        f16x4 pk;
#pragma unroll
        for (int r = 0; r < 4; ++r) pk[r] = (_Float16)(acc[i][j][r] + bb);
        *(f16x4*)(smem + cl * 132 + row) = pk;
      }
    }
    __syncthreads();
    const int n = bm >> 10, s0g = bm & 1023;
    const int vh = (bn - 1024) >> 6;
    const int cl = tid >> 1, par = tid & 1;
    const int hh = vh + (cl >> 6), d = cl & 63;
    const size_t vrow = (((size_t)((n * 8 + hh) * 64 + d)) << 10) + s0g;
#pragma unroll
    for (int g = 0; g < 8; ++g) {
      int pb = g * 16 + par * 8;
      int a32 = pb & ~31, q = (pb >> 3) & 3;
      f16x4 lo = *(const f16x4*)(smem + cl * 132 + a32 + 4 * q);
      f16x4 hi = *(const f16x4*)(smem + cl * 132 + a32 + 16 + 4 * q);
      f16x8 o = {lo[0], lo[1], lo[2], lo[3], hi[0], hi[1], hi[2], hi[3]};
      *(f16x8*)(Vt + vrow + pb) = o;
    }
  }
}

// ---------------- flash attention: 4 waves, 32 q-rows/wave, O^T epilogue ------
// 1-D grid 512: n = id&7 (XCD-pinned batch), h = (id>>3)&7, q-tile = id>>6.
// R13 structure: double-buffered K/V staging, counted vmcnt(8) across raw
// s_barrier, setprio around MFMA clusters. 80KB LDS, 2 blocks/CU.
__global__ __launch_bounds__(256, 2) void attn(
    const _Float16* __restrict__ QK, const _Float16* __restrict__ Vt,
    _Float16* __restrict__ O16) {
  __shared__ _Float16 Qs[128 * 64];
  __shared__ _Float16 Ks[2][128 * 64];
  __shared__ _Float16 Vs[2][64 * 128];
  const int tid = threadIdx.x, lane = tid & 63, w = tid >> 6;
  const int quad = lane >> 4, l15 = lane & 15;
  const int id = blockIdx.x;
  const int n = id & 7, h = (id >> 3) & 7;
  const int q0 = (id >> 6) * 128;
#pragma unroll
  for (int c = 0; c < 4; ++c) {
    int idx = c * 256 + tid;
    int row = idx >> 3, sc = idx & 7;
    int dg = sc ^ (row & 7);
    gl_lds16(QK + (size_t)(n * 1024 + q0 + row) * 1024 + h * 64 + dg * 8, Qs + idx * 8);
  }
  // prologue: stage K/V tile 0 into buffer 0 (8 gl_lds / thread)
#pragma unroll
  for (int c = 0; c < 4; ++c) {
    int idx = c * 256 + tid;
    int row = idx >> 3, sck = idx & 7;
    int dg = sck ^ (row & 7);
    gl_lds16(QK + (size_t)(n * 1024 + row) * 1024 + 512 + h * 64 + dg * 8,
             Ks[0] + idx * 8);
    int d = idx >> 4, scv = idx & 15;
    int vg = scv ^ (d & 7);
    gl_lds16(Vt + (size_t)((n * 8 + h) * 64 + d) * 1024 + vg * 8,
             Vs[0] + idx * 8);
  }
  __syncthreads();  // drains Q + KV0
  f16x8 qf[2][2];
#pragma unroll
  for (int mt = 0; mt < 2; ++mt)
#pragma unroll
    for (int dc = 0; dc < 2; ++dc) {
      int row = w * 32 + mt * 16 + l15;
      qf[mt][dc] = *(const f16x8*)(Qs + row * 64 + ((dc * 4 + quad) ^ (row & 7)) * 8);
    }
  f32x4 oaccT[4][2] = {};  // [nt d-tile][mt q-tile]: rows=d, cols=q
  f32x4 lsum[2] = {};
  const f16x8 ones = {(_Float16)1, (_Float16)1, (_Float16)1, (_Float16)1,
                      (_Float16)1, (_Float16)1, (_Float16)1, (_Float16)1};

  for (int kt = 0; kt < 8; ++kt) {
    const int cur = kt & 1;
    if (kt < 7) {
      const int nx = kt + 1;
#pragma unroll
      for (int c = 0; c < 4; ++c) {
        int idx = c * 256 + tid;
        int row = idx >> 3, sck = idx & 7;
        int dg = sck ^ (row & 7);
        gl_lds16(QK + (size_t)(n * 1024 + nx * 128 + row) * 1024 + 512 + h * 64 + dg * 8,
                 Ks[cur ^ 1] + idx * 8);
        int d = idx >> 4, scv = idx & 15;
        int vg = scv ^ (d & 7);
        gl_lds16(Vt + (size_t)((n * 8 + h) * 64 + d) * 1024 + nx * 128 + vg * 8,
                 Vs[cur ^ 1] + idx * 8);
      }
      asm volatile("s_waitcnt vmcnt(8)" ::: "memory");
    } else {
      asm volatile("s_waitcnt vmcnt(0)" ::: "memory");
    }
    __builtin_amdgcn_s_barrier();
    asm volatile("" ::: "memory");
#pragma unroll
    for (int sc = 0; sc < 4; ++sc) {
      f32x4 sacc[2][2] = {};
      __builtin_amdgcn_s_setprio(1);
#pragma unroll
      for (int t = 0; t < 2; ++t) {
        int rk = (sc * 2 + t) * 16 + l15;
        f16x8 kf0 = *(const f16x8*)(Ks[cur] + rk * 64 + ((quad) ^ (rk & 7)) * 8);
        f16x8 kf1 = *(const f16x8*)(Ks[cur] + rk * 64 + ((4 + quad) ^ (rk & 7)) * 8);
#pragma unroll
        for (int mt = 0; mt < 2; ++mt) {
          sacc[mt][t] = __builtin_amdgcn_mfma_f32_16x16x32_f16(kf0, qf[mt][0], sacc[mt][t], 0, 0, 0);
          sacc[mt][t] = __builtin_amdgcn_mfma_f32_16x16x32_f16(kf1, qf[mt][1], sacc[mt][t], 0, 0, 0);
        }
      }
      __builtin_amdgcn_s_setprio(0);
      f16x8 pf[2];
#pragma unroll
      for (int mt = 0; mt < 2; ++mt) {
#pragma unroll
        for (int t = 0; t < 2; ++t)
#pragma unroll
          for (int r = 0; r < 4; ++r)
            pf[mt][t * 4 + r] = (_Float16)fexp2(sacc[mt][t][r]);
        lsum[mt] = __builtin_amdgcn_mfma_f32_16x16x32_f16(pf[mt], ones, lsum[mt], 0, 0, 0);
      }
      __builtin_amdgcn_s_setprio(1);
#pragma unroll
      for (int nt = 0; nt < 4; ++nt) {
        int rd = nt * 16 + l15;
        f16x8 vf = *(const f16x8*)(Vs[cur] + rd * 128 + ((sc * 4 + quad) ^ (rd & 7)) * 8);
#pragma unroll
        for (int mt = 0; mt < 2; ++mt)
          oaccT[nt][mt] = __builtin_amdgcn_mfma_f32_16x16x32_f16(vf, pf[mt], oaccT[nt][mt], 0, 0, 0);
      }
      __builtin_amdgcn_s_setprio(0);
    }
    asm volatile("" ::: "memory");
    __builtin_amdgcn_s_barrier();
  }
  // epilogue: O^T layout — lane owns q = q0 + w*32 + mt*16 + l15, d = nt*16+quad*4+r.
#pragma unroll
  for (int mt = 0; mt < 2; ++mt) {
    int r3 = l15 & 3;
    float lv = lsum[mt][0];
    lv = (r3 == 1) ? lsum[mt][1] : lv;
    lv = (r3 == 2) ? lsum[mt][2] : lv;
    lv = (r3 == 3) ? lsum[mt][3] : lv;
    float lq = __shfl(lv, (l15 >> 2) * 16 + (l15 & 3), 64);
    float rinv = 1.0f / lq;
    int q = q0 + w * 32 + mt * 16 + l15;
    int i = h * 128 + (q >> 3);
    size_t base = (size_t)(n * 1024 + i) * 512 + (q & 7) * 64 + quad * 4;
#pragma unroll
    for (int nt = 0; nt < 4; ++nt) {
      f16x4 pk;
#pragma unroll
      for (int r = 0; r < 4; ++r) pk[r] = (_Float16)(oaccT[nt][mt][r] * rinv);
      *(f16x4*)(O16 + base + nt * 16) = pk;
    }
  }
}

// ---------------- out GEMM: (8192x512)*(512x512)^T + bo -> fp32 out ----------
// 1-D grid 512: BM=128, BN=64; xcd = id&7; bm-tile = xcd*8 + (k&7) (batch =
// xcd, warm from attn); bn-tile = k>>3 (0..7)*64. 2 blocks/CU, 2 waves/SIMD.
__global__ __launch_bounds__(256, 2) void out_gemm(
    const _Float16* __restrict__ A, const _Float16* __restrict__ Bw,
    const float* __restrict__ bias, float* __restrict__ out) {
  __shared__ _Float16 As[128 * 64];
  __shared__ _Float16 Bs[64 * 64];
  const int tid = threadIdx.x;
  const int lane = tid & 63, w = tid >> 6;
  const int quad = lane >> 4, l15 = lane & 15;
  const int id = blockIdx.x;
  const int xcd = id & 7, k = id >> 3;          // k 0..63
  const int bm = (xcd * 8 + (k & 7)) * 128;
  const int bn = (k >> 3) * 64;
  const int wr = (w >> 1) * 64, wc = (w & 1) * 32;
  f32x4 acc[4][2] = {};
  for (int k0 = 0; k0 < 512; k0 += 64) {
    __syncthreads();
#pragma unroll
    for (int c = 0; c < 4; ++c) {   // As: 128 rows x 8 chunks = 1024
      int idx = c * 256 + tid;
      int row = idx >> 3, sc = idx & 7;
      int kg = sc ^ (row & 7);
      gl_lds16(A + (size_t)(bm + row) * 512 + k0 + kg * 8, As + idx * 8);
    }
#pragma unroll
    for (int c = 0; c < 2; ++c) {   // Bs: 64 rows x 8 chunks = 512
      int idx = c * 256 + tid;
      int row = idx >> 3, sc = idx & 7;
      int kg = sc ^ (row & 7);
      gl_lds16(Bw + (size_t)(bn + row) * 512 + k0 + kg * 8, Bs + idx * 8);
    }
    __syncthreads();
#pragma unroll
    for (int kh = 0; kh < 2; ++kh) {
      f16x8 af[4], bf[2];
#pragma unroll
      for (int i = 0; i < 4; ++i) {
        int ra = wr + i * 16 + l15;
        af[i] = *(const f16x8*)(As + ra * 64 + ((kh * 4 + quad) ^ (ra & 7)) * 8);
      }
#pragma unroll
      for (int j = 0; j < 2; ++j) {
        int rb = wc + j * 16 + l15;
        bf[j] = *(const f16x8*)(Bs + rb * 64 + ((kh * 4 + quad) ^ (rb & 7)) * 8);
      }
#pragma unroll
      for (int i = 0; i < 4; ++i)
#pragma unroll
        for (int j = 0; j < 2; ++j)
          acc[i][j] = __builtin_amdgcn_mfma_f32_16x16x32_f16(af[i], bf[j], acc[i][j], 0, 0, 0);
    }
  }
#pragma unroll
  for (int j = 0; j < 2; ++j) {
    int col = bn + wc + j * 16 + l15;
    float bb = bias[col];
#pragma unroll
    for (int i = 0; i < 4; ++i) {
      int rowb = bm + wr + i * 16 + quad * 4;
#pragma unroll
      for (int r = 0; r < 4; ++r)
        out[(size_t)(rowb + r) * 512 + col] = acc[i][j][r] + bb;
    }
  }
}

extern "C" void kernel_launch(void* const* d_in, const int* in_sizes, int n_in,
                              void* d_out, int out_size, void* d_ws, size_t ws_size,
                              hipStream_t stream) {
  const float* x  = (const float*)d_in[0];
  const float* Wq = (const float*)d_in[1];
  const float* bq = (const float*)d_in[2];
  const float* Wk = (const float*)d_in[3];
  const float* bk = (const float*)d_in[4];
  const float* Wv = (const float*)d_in[5];
  const float* bv = (const float*)d_in[6];
  const float* Wo = (const float*)d_in[7];
  const float* bo = (const float*)d_in[8];
  float* out = (float*)d_out;
  char* ws = (char*)d_ws;

  _Float16* xs16   = (_Float16*)(ws);                          // 8 MB (reused as O16)
  _Float16* QK     = (_Float16*)(ws + (8u << 20));             // 16 MB
  _Float16* Vt     = (_Float16*)(ws + (24u << 20));            // 8 MB
  _Float16* Wqkv16 = (_Float16*)(ws + (32u << 20));            // 1.5 MB
  _Float16* Wo16   = (_Float16*)(ws + (32u << 20) + 1572864);  // 0.5 MB
  float*    bqkv   = (float*)   (ws + (32u << 20) + 2097152);  // 6 KB

  hipLaunchKernelGGL(prep, dim3(1280), dim3(256), 0, stream,
                     x, Wq, bq, Wk, bk, Wv, bv, Wo, xs16, Wqkv16, bqkv, Wo16);
  hipLaunchKernelGGL(qkv_gemm, dim3(768), dim3(256), 0, stream,
                     xs16, Wqkv16, bqkv, QK, Vt);
  hipLaunchKernelGGL(attn, dim3(512), dim3(256), 0, stream, QK, Vt, xs16);
  hipLaunchKernelGGL(out_gemm, dim3(512), dim3(256), 0, stream,
                     xs16, Wo16, bo, out);
}

// Round 7
// 131.572 us; speedup vs baseline: 1.0149x; 1.0149x over previous
//
#include <hip/hip_runtime.h>

// MultiHeadSelfAttention: N=8, C=512, heads=8, d=64, S=1024 (32x32), fp32 in/out.
// R18: attn KVBLK 128->256. Halves barrier-drain count (16 raw barriers -> 7
// __syncthreads), same staged bytes/MFMA/exp. LDS = 16+32+32 = 80KB exactly,
// 2 blocks/CU, grid 512 = exactly 2/CU. Single-buffer syncthreads protocol
// (R11-proven family; R13 measured dbuf+counted-vmcnt neutral, so dropped).
// prep/qkv_gemm/out_gemm byte-identical to R17 (passed, 133.5us).
// [R15 Q-fusion restructure: abandoned — killed container twice, and its true
//  EV was only the 16MB round-trip (~3us) since Q-projection work just moves.]

typedef _Float16 f16x8 __attribute__((ext_vector_type(8)));
typedef _Float16 f16x4 __attribute__((ext_vector_type(4)));
typedef float f32x4 __attribute__((ext_vector_type(4)));

__device__ inline void gl_lds16(const void* g, void* l) {
  __builtin_amdgcn_global_load_lds((const __attribute__((address_space(1))) void*)g,
                                   (__attribute__((address_space(3))) void*)l, 16, 0, 0);
}

__device__ inline float fexp2(float x) {
#if __has_builtin(__builtin_amdgcn_exp2f)
  return __builtin_amdgcn_exp2f(x);
#else
  return exp2f(x);
#endif
}

// ---------------- prep: weight cast (vec) + x transpose+cast (vec) -----------
// blocks [0,256): weights/bias. blocks [256,1280): x-part, 64c x 64s tiles,
// n = (bid-256)&7 -> XCD-pinned batch.
__global__ void prep(const float* __restrict__ x,
                     const float* __restrict__ Wq, const float* __restrict__ bq,
                     const float* __restrict__ Wk, const float* __restrict__ bk,
                     const float* __restrict__ Wv, const float* __restrict__ bv,
                     const float* __restrict__ Wo,
                     _Float16* __restrict__ xs16, _Float16* __restrict__ Wqkv16,
                     float* __restrict__ bqkv, _Float16* __restrict__ Wo16) {
  const int tid = threadIdx.x;
  const int bid = blockIdx.x;
  const float g = 0.18033688011112042f;  // log2(e)/8
  if (bid < 256) {
    int i4 = (bid * 256 + tid) * 4;
    float4 q = *(const float4*)(Wq + i4);
    float4 k = *(const float4*)(Wk + i4);
    float4 v = *(const float4*)(Wv + i4);
    float4 o = *(const float4*)(Wo + i4);
    f16x4 qh = {(_Float16)(q.x * g), (_Float16)(q.y * g),
                (_Float16)(q.z * g), (_Float16)(q.w * g)};
    f16x4 kh = {(_Float16)k.x, (_Float16)k.y, (_Float16)k.z, (_Float16)k.w};
    f16x4 vh = {(_Float16)v.x, (_Float16)v.y, (_Float16)v.z, (_Float16)v.w};
    f16x4 oh = {(_Float16)o.x, (_Float16)o.y, (_Float16)o.z, (_Float16)o.w};
    *(f16x4*)(Wqkv16 + i4)          = qh;
    *(f16x4*)(Wqkv16 + 262144 + i4) = kh;
    *(f16x4*)(Wqkv16 + 524288 + i4) = vh;
    *(f16x4*)(Wo16 + i4)            = oh;
    if (bid == 0 && tid < 128) {
      int t4 = tid * 4;
      float4 b1 = *(const float4*)(bq + t4);
      float4 b2 = *(const float4*)(bk + t4);
      float4 b3 = *(const float4*)(bv + t4);
      b1.x *= g; b1.y *= g; b1.z *= g; b1.w *= g;
      *(float4*)(bqkv + t4)        = b1;
      *(float4*)(bqkv + 512 + t4)  = b2;
      *(float4*)(bqkv + 1024 + t4) = b3;
    }
    return;
  }
  __shared__ float t[64][65];
  const int bid2 = bid - 256;                   // 0..1023
  const int n = bid2 & 7;                       // XCD-pinned batch
  const int r7 = bid2 >> 3;                     // 0..127
  const int c0 = (r7 & 7) * 64, s0 = (r7 >> 3) * 64;
#pragma unroll
  for (int i = 0; i < 4; ++i) {
    int idx = i * 256 + tid;
    int rr = idx >> 4, cq = (idx & 15) * 4;     // rr = channel, cq = s offset
    float4 xv = *(const float4*)(x + (size_t)(n * 512 + c0 + rr) * 1024 + s0 + cq);
    t[rr][cq] = xv.x; t[rr][cq + 1] = xv.y; t[rr][cq + 2] = xv.z; t[rr][cq + 3] = xv.w;
  }
  __syncthreads();
#pragma unroll
  for (int i = 0; i < 2; ++i) {
    int idx = i * 256 + tid;
    int ss = idx >> 3, c8 = (idx & 7) * 8;      // ss = s offset, c8 = channel base
    f16x8 o;
#pragma unroll
    for (int kk = 0; kk < 8; ++kk) o[kk] = (_Float16)t[c8 + kk][ss];
    *(f16x8*)(xs16 + (size_t)(n * 1024 + s0 + ss) * 512 + c0 + c8) = o;
  }
}

// ---------------- QKV GEMM: (8192x512)*(1536x512)^T + bias, BK=64 ------------
// 1-D grid 768: xcd = id&7; k = id>>3; bm-tile = xcd*8 + (k&7) (batch = xcd);
// bn-tile = k>>3. Per-XCD: A 1MB + B 1.5MB fits 4MB L2.
// launch_bounds(256,3) -> 3 blocks/CU, grid 768 = exactly 3/CU, no tail.
__global__ __launch_bounds__(256, 3) void qkv_gemm(
    const _Float16* __restrict__ A, const _Float16* __restrict__ Bw,
    const float* __restrict__ bias, _Float16* __restrict__ QK,
    _Float16* __restrict__ Vt) {
  __shared__ _Float16 smem[16896];  // K-loop: As[0:8192) Bs[8192:16384); epi T 128x132
  _Float16* As = smem;
  _Float16* Bs = smem + 8192;
  const int tid = threadIdx.x;
  const int lane = tid & 63, w = tid >> 6;
  const int quad = lane >> 4, l15 = lane & 15;
  const int id = blockIdx.x;
  const int xcd = id & 7, k = id >> 3;
  const int bm = (xcd * 8 + (k & 7)) * 128;     // batch = xcd
  const int bnt = k >> 3;                       // 0..11
  const int bn = bnt * 128;
  const int wr = (w >> 1) * 64, wc = (w & 1) * 64;
  f32x4 acc[4][4] = {};
  for (int k0 = 0; k0 < 512; k0 += 64) {
    __syncthreads();
#pragma unroll
    for (int c = 0; c < 4; ++c) {
      int idx = c * 256 + tid;          // 0..1023
      int row = idx >> 3, sc = idx & 7;
      int kg = sc ^ (row & 7);          // XOR-chunk swizzle (8 chunks/row)
      gl_lds16(A + (size_t)(bm + row) * 512 + k0 + kg * 8, As + idx * 8);
      gl_lds16(Bw + (size_t)(bn + row) * 512 + k0 + kg * 8, Bs + idx * 8);
    }
    __syncthreads();
#pragma unroll
    for (int kh = 0; kh < 2; ++kh) {
      f16x8 af[4], bf[4];
#pragma unroll
      for (int i = 0; i < 4; ++i) {
        int ra = wr + i * 16 + l15;
        af[i] = *(const f16x8*)(As + ra * 64 + ((kh * 4 + quad) ^ (ra & 7)) * 8);
        int rb = wc + i * 16 + l15;
        bf[i] = *(const f16x8*)(Bs + rb * 64 + ((kh * 4 + quad) ^ (rb & 7)) * 8);
      }
#pragma unroll
      for (int i = 0; i < 4; ++i)
#pragma unroll
        for (int j = 0; j < 4; ++j)
          acc[i][j] = __builtin_amdgcn_mfma_f32_16x16x32_f16(af[i], bf[j], acc[i][j], 0, 0, 0);
    }
  }
  if (bnt < 8) {
    // Q/K blocks: direct store (lanes contiguous in col -> coalesced)
#pragma unroll
    for (int j = 0; j < 4; ++j) {
      int col = bn + wc + j * 16 + l15;
      float bb = bias[col];
#pragma unroll
      for (int i = 0; i < 4; ++i) {
        int rowb = bm + wr + i * 16 + quad * 4;
#pragma unroll
        for (int r = 0; r < 4; ++r)
          QK[(size_t)(rowb + r) * 1024 + col] = (_Float16)(acc[i][j][r] + bb);
      }
    }
  } else {
    // V blocks: transpose tile through LDS, store coalesced with s-permutation
    __syncthreads();  // As/Bs dead; reuse smem as T[col][row], stride 132
#pragma unroll
    for (int j = 0; j < 4; ++j) {
      int cl = wc + j * 16 + l15;
      float bb = bias[bn + cl];
#pragma unroll
      for (int i = 0; i < 4; ++i) {
        int row = wr + i * 16 + quad * 4;
        f16x4 pk;
#pragma unroll
        for (int r = 0; r < 4; ++r) pk[r] = (_Float16)(acc[i][j][r] + bb);
        *(f16x4*)(smem + cl * 132 + row) = pk;
      }
    }
    __syncthreads();
    const int n = bm >> 10, s0g = bm & 1023;
    const int vh = (bn - 1024) >> 6;
    const int cl = tid >> 1, par = tid & 1;
    const int hh = vh + (cl >> 6), d = cl & 63;
    const size_t vrow = (((size_t)((n * 8 + hh) * 64 + d)) << 10) + s0g;
#pragma unroll
    for (int g = 0; g < 8; ++g) {
      int pb = g * 16 + par * 8;
      int a32 = pb & ~31, q = (pb >> 3) & 3;
      f16x4 lo = *(const f16x4*)(smem + cl * 132 + a32 + 4 * q);
      f16x4 hi = *(const f16x4*)(smem + cl * 132 + a32 + 16 + 4 * q);
      f16x8 o = {lo[0], lo[1], lo[2], lo[3], hi[0], hi[1], hi[2], hi[3]};
      *(f16x8*)(Vt + vrow + pb) = o;
    }
  }
}

// ---------------- flash attention: 4 waves, 32 q-rows/wave, O^T epilogue ------
// 1-D grid 512: n = id&7 (XCD-pinned batch), h = (id>>3)&7, q-tile = id>>6.
// R18: KVBLK=256, single-buffer, 4 kt iterations, 7 __syncthreads total.
// LDS: Qs 16KB + Ks 32KB + Vs 32KB = 80KB -> 2 blocks/CU (grid = exactly 2/CU).
__global__ __launch_bounds__(256, 2) void attn(
    const _Float16* __restrict__ QK, const _Float16* __restrict__ Vt,
    _Float16* __restrict__ O16) {
  __shared__ _Float16 Qs[128 * 64];
  __shared__ _Float16 Ks[256 * 64];
  __shared__ _Float16 Vs[64 * 256];
  const int tid = threadIdx.x, lane = tid & 63, w = tid >> 6;
  const int quad = lane >> 4, l15 = lane & 15;
  const int id = blockIdx.x;
  const int n = id & 7, h = (id >> 3) & 7;
  const int q0 = (id >> 6) * 128;
  // stage Q (4 gl_lds / thread)
#pragma unroll
  for (int c = 0; c < 4; ++c) {
    int idx = c * 256 + tid;
    int row = idx >> 3, sc = idx & 7;
    int dg = sc ^ (row & 7);
    gl_lds16(QK + (size_t)(n * 1024 + q0 + row) * 1024 + h * 64 + dg * 8, Qs + idx * 8);
  }
  // stage K/V tile 0 (16 gl_lds / thread)
#pragma unroll
  for (int c = 0; c < 8; ++c) {
    int idx = c * 256 + tid;                    // 0..2047
    int row = idx >> 3, sck = idx & 7;
    int dg = sck ^ (row & 7);
    gl_lds16(QK + (size_t)(n * 1024 + row) * 1024 + 512 + h * 64 + dg * 8,
             Ks + idx * 8);
    int d = idx >> 5, scv = idx & 31;
    int vg = scv ^ (d & 7);
    gl_lds16(Vt + (size_t)((n * 8 + h) * 64 + d) * 1024 + vg * 8,
             Vs + idx * 8);
  }
  __syncthreads();  // drains Q + KV0
  f16x8 qf[2][2];
#pragma unroll
  for (int mt = 0; mt < 2; ++mt)
#pragma unroll
    for (int dc = 0; dc < 2; ++dc) {
      int row = w * 32 + mt * 16 + l15;
      qf[mt][dc] = *(const f16x8*)(Qs + row * 64 + ((dc * 4 + quad) ^ (row & 7)) * 8);
    }
  f32x4 oaccT[4][2] = {};  // [nt d-tile][mt q-tile]: rows=d, cols=q
  f32x4 lsum[2] = {};
  const f16x8 ones = {(_Float16)1, (_Float16)1, (_Float16)1, (_Float16)1,
                      (_Float16)1, (_Float16)1, (_Float16)1, (_Float16)1};

  for (int kt = 0; kt < 4; ++kt) {
#pragma unroll
    for (int sc = 0; sc < 8; ++sc) {
      f32x4 sacc[2][2] = {};
      __builtin_amdgcn_s_setprio(1);
#pragma unroll
      for (int t = 0; t < 2; ++t) {
        int rk = (sc * 2 + t) * 16 + l15;
        f16x8 kf0 = *(const f16x8*)(Ks + rk * 64 + ((quad) ^ (rk & 7)) * 8);
        f16x8 kf1 = *(const f16x8*)(Ks + rk * 64 + ((4 + quad) ^ (rk & 7)) * 8);
#pragma unroll
        for (int mt = 0; mt < 2; ++mt) {
          sacc[mt][t] = __builtin_amdgcn_mfma_f32_16x16x32_f16(kf0, qf[mt][0], sacc[mt][t], 0, 0, 0);
          sacc[mt][t] = __builtin_amdgcn_mfma_f32_16x16x32_f16(kf1, qf[mt][1], sacc[mt][t], 0, 0, 0);
        }
      }
      __builtin_amdgcn_s_setprio(0);
      f16x8 pf[2];
#pragma unroll
      for (int mt = 0; mt < 2; ++mt) {
#pragma unroll
        for (int t = 0; t < 2; ++t)
#pragma unroll
          for (int r = 0; r < 4; ++r)
            pf[mt][t * 4 + r] = (_Float16)fexp2(sacc[mt][t][r]);
        lsum[mt] = __builtin_amdgcn_mfma_f32_16x16x32_f16(pf[mt], ones, lsum[mt], 0, 0, 0);
      }
      __builtin_amdgcn_s_setprio(1);
#pragma unroll
      for (int nt = 0; nt < 4; ++nt) {
        int rd = nt * 16 + l15;
        f16x8 vf = *(const f16x8*)(Vs + rd * 256 + ((sc * 4 + quad) ^ (rd & 7)) * 8);
#pragma unroll
        for (int mt = 0; mt < 2; ++mt)
          oaccT[nt][mt] = __builtin_amdgcn_mfma_f32_16x16x32_f16(vf, pf[mt], oaccT[nt][mt], 0, 0, 0);
      }
      __builtin_amdgcn_s_setprio(0);
    }
    if (kt < 3) {
      __syncthreads();  // all waves done reading Ks/Vs
      const int nx = kt + 1;
#pragma unroll
      for (int c = 0; c < 8; ++c) {
        int idx = c * 256 + tid;
        int row = idx >> 3, sck = idx & 7;
        int dg = sck ^ (row & 7);
        gl_lds16(QK + (size_t)(n * 1024 + nx * 256 + row) * 1024 + 512 + h * 64 + dg * 8,
                 Ks + idx * 8);
        int d = idx >> 5, scv = idx & 31;
        int vg = scv ^ (d & 7);
        gl_lds16(Vt + (size_t)((n * 8 + h) * 64 + d) * 1024 + nx * 256 + vg * 8,
                 Vs + idx * 8);
      }
      __syncthreads();  // drain next tile
    }
  }
  // epilogue: O^T layout — lane owns q = q0 + w*32 + mt*16 + l15, d = nt*16+quad*4+r.
#pragma unroll
  for (int mt = 0; mt < 2; ++mt) {
    int r3 = l15 & 3;
    float lv = lsum[mt][0];
    lv = (r3 == 1) ? lsum[mt][1] : lv;
    lv = (r3 == 2) ? lsum[mt][2] : lv;
    lv = (r3 == 3) ? lsum[mt][3] : lv;
    float lq = __shfl(lv, (l15 >> 2) * 16 + (l15 & 3), 64);
    float rinv = 1.0f / lq;
    int q = q0 + w * 32 + mt * 16 + l15;
    int i = h * 128 + (q >> 3);
    size_t base = (size_t)(n * 1024 + i) * 512 + (q & 7) * 64 + quad * 4;
#pragma unroll
    for (int nt = 0; nt < 4; ++nt) {
      f16x4 pk;
#pragma unroll
      for (int r = 0; r < 4; ++r) pk[r] = (_Float16)(oaccT[nt][mt][r] * rinv);
      *(f16x4*)(O16 + base + nt * 16) = pk;
    }
  }
}

// ---------------- out GEMM: (8192x512)*(512x512)^T + bo -> fp32 out ----------
// 1-D grid 512: BM=128, BN=64; xcd = id&7; bm-tile = xcd*8 + (k&7) (batch =
// xcd, warm from attn); bn-tile = k>>3 (0..7)*64. 2 blocks/CU, 2 waves/SIMD.
__global__ __launch_bounds__(256, 2) void out_gemm(
    const _Float16* __restrict__ A, const _Float16* __restrict__ Bw,
    const float* __restrict__ bias, float* __restrict__ out) {
  __shared__ _Float16 As[128 * 64];
  __shared__ _Float16 Bs[64 * 64];
  const int tid = threadIdx.x;
  const int lane = tid & 63, w = tid >> 6;
  const int quad = lane >> 4, l15 = lane & 15;
  const int id = blockIdx.x;
  const int xcd = id & 7, k = id >> 3;          // k 0..63
  const int bm = (xcd * 8 + (k & 7)) * 128;
  const int bn = (k >> 3) * 64;
  const int wr = (w >> 1) * 64, wc = (w & 1) * 32;
  f32x4 acc[4][2] = {};
  for (int k0 = 0; k0 < 512; k0 += 64) {
    __syncthreads();
#pragma unroll
    for (int c = 0; c < 4; ++c) {   // As: 128 rows x 8 chunks = 1024
      int idx = c * 256 + tid;
      int row = idx >> 3, sc = idx & 7;
      int kg = sc ^ (row & 7);
      gl_lds16(A + (size_t)(bm + row) * 512 + k0 + kg * 8, As + idx * 8);
    }
#pragma unroll
    for (int c = 0; c < 2; ++c) {   // Bs: 64 rows x 8 chunks = 512
      int idx = c * 256 + tid;
      int row = idx >> 3, sc = idx & 7;
      int kg = sc ^ (row & 7);
      gl_lds16(Bw + (size_t)(bn + row) * 512 + k0 + kg * 8, Bs + idx * 8);
    }
    __syncthreads();
#pragma unroll
    for (int kh = 0; kh < 2; ++kh) {
      f16x8 af[4], bf[2];
#pragma unroll
      for (int i = 0; i < 4; ++i) {
        int ra = wr + i * 16 + l15;
        af[i] = *(const f16x8*)(As + ra * 64 + ((kh * 4 + quad) ^ (ra & 7)) * 8);
      }
#pragma unroll
      for (int j = 0; j < 2; ++j) {
        int rb = wc + j * 16 + l15;
        bf[j] = *(const f16x8*)(Bs + rb * 64 + ((kh * 4 + quad) ^ (rb & 7)) * 8);
      }
#pragma unroll
      for (int i = 0; i < 4; ++i)
#pragma unroll
        for (int j = 0; j < 2; ++j)
          acc[i][j] = __builtin_amdgcn_mfma_f32_16x16x32_f16(af[i], bf[j], acc[i][j], 0, 0, 0);
    }
  }
#pragma unroll
  for (int j = 0; j < 2; ++j) {
    int col = bn + wc + j * 16 + l15;
    float bb = bias[col];
#pragma unroll
    for (int i = 0; i < 4; ++i) {
      int rowb = bm + wr + i * 16 + quad * 4;
#pragma unroll
      for (int r = 0; r < 4; ++r)
        out[(size_t)(rowb + r) * 512 + col] = acc[i][j][r] + bb;
    }
  }
}

extern "C" void kernel_launch(void* const* d_in, const int* in_sizes, int n_in,
                              void* d_out, int out_size, void* d_ws, size_t ws_size,
                              hipStream_t stream) {
  const float* x  = (const float*)d_in[0];
  const float* Wq = (const float*)d_in[1];
  const float* bq = (const float*)d_in[2];
  const float* Wk = (const float*)d_in[3];
  const float* bk = (const float*)d_in[4];
  const float* Wv = (const float*)d_in[5];
  const float* bv = (const float*)d_in[6];
  const float* Wo = (const float*)d_in[7];
  const float* bo = (const float*)d_in[8];
  float* out = (float*)d_out;
  char* ws = (char*)d_ws;

  _Float16* xs16   = (_Float16*)(ws);                          // 8 MB (reused as O16)
  _Float16* QK     = (_Float16*)(ws + (8u << 20));             // 16 MB
  _Float16* Vt     = (_Float16*)(ws + (24u << 20));            // 8 MB
  _Float16* Wqkv16 = (_Float16*)(ws + (32u << 20));            // 1.5 MB
  _Float16* Wo16   = (_Float16*)(ws + (32u << 20) + 1572864);  // 0.5 MB
  float*    bqkv   = (float*)   (ws + (32u << 20) + 2097152);  // 6 KB

  hipLaunchKernelGGL(prep, dim3(1280), dim3(256), 0, stream,
                     x, Wq, bq, Wk, bk, Wv, bv, Wo, xs16, Wqkv16, bqkv, Wo16);
  hipLaunchKernelGGL(qkv_gemm, dim3(768), dim3(256), 0, stream,
                     xs16, Wqkv16, bqkv, QK, Vt);
  hipLaunchKernelGGL(attn, dim3(512), dim3(256), 0, stream, QK, Vt, xs16);
  hipLaunchKernelGGL(out_gemm, dim3(512), dim3(256), 0, stream,
                     xs16, Wo16, bo, out);
}

// Round 9
// 130.263 us; speedup vs baseline: 1.0251x; 1.0100x over previous
//
#include <hip/hip_runtime.h>

// MultiHeadSelfAttention: N=8, C=512, heads=8, d=64, S=1024 (32x32), fp32 in/out.
// R20 = R19 with compile fix: __builtin_amdgcn_cvt_pkrtz returns __fp16-vec2,
// bit_cast to _Float16-vec2 (same bits). No other change.
// R19: two low-risk micro-opts on the R18 base (131.6us, best).
//  - attn: pf conversion via packed v_cvt_pkrtz_f16_f32 (16 pk-cvts vs 32
//    scalar cvts in the VALU-bound softmax phase).
//  - out_gemm: BK 64->128 (barrier halving): 4 k-iters, 8 barriers (was 16).
//    LDS 32+16=48KB, still 2 blocks/CU.
//  - prep/qkv_gemm byte-identical to R18 (attribution anchors).

typedef _Float16 f16x8 __attribute__((ext_vector_type(8)));
typedef _Float16 f16x4 __attribute__((ext_vector_type(4)));
typedef _Float16 f16x2 __attribute__((ext_vector_type(2)));
typedef __fp16 h16x2 __attribute__((ext_vector_type(2)));
typedef float f32x4 __attribute__((ext_vector_type(4)));

__device__ inline void gl_lds16(const void* g, void* l) {
  __builtin_amdgcn_global_load_lds((const __attribute__((address_space(1))) void*)g,
                                   (__attribute__((address_space(3))) void*)l, 16, 0, 0);
}

__device__ inline float fexp2(float x) {
#if __has_builtin(__builtin_amdgcn_exp2f)
  return __builtin_amdgcn_exp2f(x);
#else
  return exp2f(x);
#endif
}

__device__ inline f16x2 pk2(float a, float b) {
#if __has_builtin(__builtin_amdgcn_cvt_pkrtz)
  h16x2 t = __builtin_amdgcn_cvt_pkrtz(a, b);
  return __builtin_bit_cast(f16x2, t);
#else
  f16x2 r; r[0] = (_Float16)a; r[1] = (_Float16)b; return r;
#endif
}

// ---------------- prep: weight cast (vec) + x transpose+cast (vec) -----------
// blocks [0,256): weights/bias. blocks [256,1280): x-part, 64c x 64s tiles,
// n = (bid-256)&7 -> XCD-pinned batch.
__global__ void prep(const float* __restrict__ x,
                     const float* __restrict__ Wq, const float* __restrict__ bq,
                     const float* __restrict__ Wk, const float* __restrict__ bk,
                     const float* __restrict__ Wv, const float* __restrict__ bv,
                     const float* __restrict__ Wo,
                     _Float16* __restrict__ xs16, _Float16* __restrict__ Wqkv16,
                     float* __restrict__ bqkv, _Float16* __restrict__ Wo16) {
  const int tid = threadIdx.x;
  const int bid = blockIdx.x;
  const float g = 0.18033688011112042f;  // log2(e)/8
  if (bid < 256) {
    int i4 = (bid * 256 + tid) * 4;
    float4 q = *(const float4*)(Wq + i4);
    float4 k = *(const float4*)(Wk + i4);
    float4 v = *(const float4*)(Wv + i4);
    float4 o = *(const float4*)(Wo + i4);
    f16x4 qh = {(_Float16)(q.x * g), (_Float16)(q.y * g),
                (_Float16)(q.z * g), (_Float16)(q.w * g)};
    f16x4 kh = {(_Float16)k.x, (_Float16)k.y, (_Float16)k.z, (_Float16)k.w};
    f16x4 vh = {(_Float16)v.x, (_Float16)v.y, (_Float16)v.z, (_Float16)v.w};
    f16x4 oh = {(_Float16)o.x, (_Float16)o.y, (_Float16)o.z, (_Float16)o.w};
    *(f16x4*)(Wqkv16 + i4)          = qh;
    *(f16x4*)(Wqkv16 + 262144 + i4) = kh;
    *(f16x4*)(Wqkv16 + 524288 + i4) = vh;
    *(f16x4*)(Wo16 + i4)            = oh;
    if (bid == 0 && tid < 128) {
      int t4 = tid * 4;
      float4 b1 = *(const float4*)(bq + t4);
      float4 b2 = *(const float4*)(bk + t4);
      float4 b3 = *(const float4*)(bv + t4);
      b1.x *= g; b1.y *= g; b1.z *= g; b1.w *= g;
      *(float4*)(bqkv + t4)        = b1;
      *(float4*)(bqkv + 512 + t4)  = b2;
      *(float4*)(bqkv + 1024 + t4) = b3;
    }
    return;
  }
  __shared__ float t[64][65];
  const int bid2 = bid - 256;                   // 0..1023
  const int n = bid2 & 7;                       // XCD-pinned batch
  const int r7 = bid2 >> 3;                     // 0..127
  const int c0 = (r7 & 7) * 64, s0 = (r7 >> 3) * 64;
#pragma unroll
  for (int i = 0; i < 4; ++i) {
    int idx = i * 256 + tid;
    int rr = idx >> 4, cq = (idx & 15) * 4;     // rr = channel, cq = s offset
    float4 xv = *(const float4*)(x + (size_t)(n * 512 + c0 + rr) * 1024 + s0 + cq);
    t[rr][cq] = xv.x; t[rr][cq + 1] = xv.y; t[rr][cq + 2] = xv.z; t[rr][cq + 3] = xv.w;
  }
  __syncthreads();
#pragma unroll
  for (int i = 0; i < 2; ++i) {
    int idx = i * 256 + tid;
    int ss = idx >> 3, c8 = (idx & 7) * 8;      // ss = s offset, c8 = channel base
    f16x8 o;
#pragma unroll
    for (int kk = 0; kk < 8; ++kk) o[kk] = (_Float16)t[c8 + kk][ss];
    *(f16x8*)(xs16 + (size_t)(n * 1024 + s0 + ss) * 512 + c0 + c8) = o;
  }
}

// ---------------- QKV GEMM: (8192x512)*(1536x512)^T + bias, BK=64 ------------
// 1-D grid 768: xcd = id&7; k = id>>3; bm-tile = xcd*8 + (k&7) (batch = xcd);
// bn-tile = k>>3. Per-XCD: A 1MB + B 1.5MB fits 4MB L2.
// launch_bounds(256,3) -> 3 blocks/CU, grid 768 = exactly 3/CU, no tail.
__global__ __launch_bounds__(256, 3) void qkv_gemm(
    const _Float16* __restrict__ A, const _Float16* __restrict__ Bw,
    const float* __restrict__ bias, _Float16* __restrict__ QK,
    _Float16* __restrict__ Vt) {
  __shared__ _Float16 smem[16896];  // K-loop: As[0:8192) Bs[8192:16384); epi T 128x132
  _Float16* As = smem;
  _Float16* Bs = smem + 8192;
  const int tid = threadIdx.x;
  const int lane = tid & 63, w = tid >> 6;
  const int quad = lane >> 4, l15 = lane & 15;
  const int id = blockIdx.x;
  const int xcd = id & 7, k = id >> 3;
  const int bm = (xcd * 8 + (k & 7)) * 128;     // batch = xcd
  const int bnt = k >> 3;                       // 0..11
  const int bn = bnt * 128;
  const int wr = (w >> 1) * 64, wc = (w & 1) * 64;
  f32x4 acc[4][4] = {};
  for (int k0 = 0; k0 < 512; k0 += 64) {
    __syncthreads();
#pragma unroll
    for (int c = 0; c < 4; ++c) {
      int idx = c * 256 + tid;          // 0..1023
      int row = idx >> 3, sc = idx & 7;
      int kg = sc ^ (row & 7);          // XOR-chunk swizzle (8 chunks/row)
      gl_lds16(A + (size_t)(bm + row) * 512 + k0 + kg * 8, As + idx * 8);
      gl_lds16(Bw + (size_t)(bn + row) * 512 + k0 + kg * 8, Bs + idx * 8);
    }
    __syncthreads();
#pragma unroll
    for (int kh = 0; kh < 2; ++kh) {
      f16x8 af[4], bf[4];
#pragma unroll
      for (int i = 0; i < 4; ++i) {
        int ra = wr + i * 16 + l15;
        af[i] = *(const f16x8*)(As + ra * 64 + ((kh * 4 + quad) ^ (ra & 7)) * 8);
        int rb = wc + i * 16 + l15;
        bf[i] = *(const f16x8*)(Bs + rb * 64 + ((kh * 4 + quad) ^ (rb & 7)) * 8);
      }
#pragma unroll
      for (int i = 0; i < 4; ++i)
#pragma unroll
        for (int j = 0; j < 4; ++j)
          acc[i][j] = __builtin_amdgcn_mfma_f32_16x16x32_f16(af[i], bf[j], acc[i][j], 0, 0, 0);
    }
  }
  if (bnt < 8) {
    // Q/K blocks: direct store (lanes contiguous in col -> coalesced)
#pragma unroll
    for (int j = 0; j < 4; ++j) {
      int col = bn + wc + j * 16 + l15;
      float bb = bias[col];
#pragma unroll
      for (int i = 0; i < 4; ++i) {
        int rowb = bm + wr + i * 16 + quad * 4;
#pragma unroll
        for (int r = 0; r < 4; ++r)
          QK[(size_t)(rowb + r) * 1024 + col] = (_Float16)(acc[i][j][r] + bb);
      }
    }
  } else {
    // V blocks: transpose tile through LDS, store coalesced with s-permutation
    __syncthreads();  // As/Bs dead; reuse smem as T[col][row], stride 132
#pragma unroll
    for (int j = 0; j < 4; ++j) {
      int cl = wc + j * 16 + l15;
      float bb = bias[bn + cl];
#pragma unroll
      for (int i = 0; i < 4; ++i) {
        int row = wr + i * 16 + quad * 4;
        f16x4 pk;
#pragma unroll
        for (int r = 0; r < 4; ++r) pk[r] = (_Float16)(acc[i][j][r] + bb);
        *(f16x4*)(smem + cl * 132 + row) = pk;
      }
    }
    __syncthreads();
    const int n = bm >> 10, s0g = bm & 1023;
    const int vh = (bn - 1024) >> 6;
    const int cl = tid >> 1, par = tid & 1;
    const int hh = vh + (cl >> 6), d = cl & 63;
    const size_t vrow = (((size_t)((n * 8 + hh) * 64 + d)) << 10) + s0g;
#pragma unroll
    for (int g = 0; g < 8; ++g) {
      int pb = g * 16 + par * 8;
      int a32 = pb & ~31, q = (pb >> 3) & 3;
      f16x4 lo = *(const f16x4*)(smem + cl * 132 + a32 + 4 * q);
      f16x4 hi = *(const f16x4*)(smem + cl * 132 + a32 + 16 + 4 * q);
      f16x8 o = {lo[0], lo[1], lo[2], lo[3], hi[0], hi[1], hi[2], hi[3]};
      *(f16x8*)(Vt + vrow + pb) = o;
    }
  }
}

// ---------------- flash attention: 4 waves, 32 q-rows/wave, O^T epilogue ------
// 1-D grid 512: n = id&7 (XCD-pinned batch), h = (id>>3)&7, q-tile = id>>6.
// R18 structure: KVBLK=256, single-buffer, 4 kt iterations, 7 __syncthreads.
// R19/R20: pf via packed v_cvt_pkrtz (16 pk-cvts/phase instead of 32 scalar).
__global__ __launch_bounds__(256, 2) void attn(
    const _Float16* __restrict__ QK, const _Float16* __restrict__ Vt,
    _Float16* __restrict__ O16) {
  __shared__ _Float16 Qs[128 * 64];
  __shared__ _Float16 Ks[256 * 64];
  __shared__ _Float16 Vs[64 * 256];
  const int tid = threadIdx.x, lane = tid & 63, w = tid >> 6;
  const int quad = lane >> 4, l15 = lane & 15;
  const int id = blockIdx.x;
  const int n = id & 7, h = (id >> 3) & 7;
  const int q0 = (id >> 6) * 128;
  // stage Q (4 gl_lds / thread)
#pragma unroll
  for (int c = 0; c < 4; ++c) {
    int idx = c * 256 + tid;
    int row = idx >> 3, sc = idx & 7;
    int dg = sc ^ (row & 7);
    gl_lds16(QK + (size_t)(n * 1024 + q0 + row) * 1024 + h * 64 + dg * 8, Qs + idx * 8);
  }
  // stage K/V tile 0 (16 gl_lds / thread)
#pragma unroll
  for (int c = 0; c < 8; ++c) {
    int idx = c * 256 + tid;                    // 0..2047
    int row = idx >> 3, sck = idx & 7;
    int dg = sck ^ (row & 7);
    gl_lds16(QK + (size_t)(n * 1024 + row) * 1024 + 512 + h * 64 + dg * 8,
             Ks + idx * 8);
    int d = idx >> 5, scv = idx & 31;
    int vg = scv ^ (d & 7);
    gl_lds16(Vt + (size_t)((n * 8 + h) * 64 + d) * 1024 + vg * 8,
             Vs + idx * 8);
  }
  __syncthreads();  // drains Q + KV0
  f16x8 qf[2][2];
#pragma unroll
  for (int mt = 0; mt < 2; ++mt)
#pragma unroll
    for (int dc = 0; dc < 2; ++dc) {
      int row = w * 32 + mt * 16 + l15;
      qf[mt][dc] = *(const f16x8*)(Qs + row * 64 + ((dc * 4 + quad) ^ (row & 7)) * 8);
    }
  f32x4 oaccT[4][2] = {};  // [nt d-tile][mt q-tile]: rows=d, cols=q
  f32x4 lsum[2] = {};
  const f16x8 ones = {(_Float16)1, (_Float16)1, (_Float16)1, (_Float16)1,
                      (_Float16)1, (_Float16)1, (_Float16)1, (_Float16)1};

  for (int kt = 0; kt < 4; ++kt) {
#pragma unroll
    for (int sc = 0; sc < 8; ++sc) {
      f32x4 sacc[2][2] = {};
      __builtin_amdgcn_s_setprio(1);
#pragma unroll
      for (int t = 0; t < 2; ++t) {
        int rk = (sc * 2 + t) * 16 + l15;
        f16x8 kf0 = *(const f16x8*)(Ks + rk * 64 + ((quad) ^ (rk & 7)) * 8);
        f16x8 kf1 = *(const f16x8*)(Ks + rk * 64 + ((4 + quad) ^ (rk & 7)) * 8);
#pragma unroll
        for (int mt = 0; mt < 2; ++mt) {
          sacc[mt][t] = __builtin_amdgcn_mfma_f32_16x16x32_f16(kf0, qf[mt][0], sacc[mt][t], 0, 0, 0);
          sacc[mt][t] = __builtin_amdgcn_mfma_f32_16x16x32_f16(kf1, qf[mt][1], sacc[mt][t], 0, 0, 0);
        }
      }
      __builtin_amdgcn_s_setprio(0);
      f16x8 pf[2];
#pragma unroll
      for (int mt = 0; mt < 2; ++mt) {
        // packed f32->f16 conversion: each f16x2 = one VGPR of the f16x8 operand
        f16x2 p0 = pk2(fexp2(sacc[mt][0][0]), fexp2(sacc[mt][0][1]));
        f16x2 p1 = pk2(fexp2(sacc[mt][0][2]), fexp2(sacc[mt][0][3]));
        f16x2 p2 = pk2(fexp2(sacc[mt][1][0]), fexp2(sacc[mt][1][1]));
        f16x2 p3 = pk2(fexp2(sacc[mt][1][2]), fexp2(sacc[mt][1][3]));
        pf[mt][0] = p0[0]; pf[mt][1] = p0[1];
        pf[mt][2] = p1[0]; pf[mt][3] = p1[1];
        pf[mt][4] = p2[0]; pf[mt][5] = p2[1];
        pf[mt][6] = p3[0]; pf[mt][7] = p3[1];
        lsum[mt] = __builtin_amdgcn_mfma_f32_16x16x32_f16(pf[mt], ones, lsum[mt], 0, 0, 0);
      }
      __builtin_amdgcn_s_setprio(1);
#pragma unroll
      for (int nt = 0; nt < 4; ++nt) {
        int rd = nt * 16 + l15;
        f16x8 vf = *(const f16x8*)(Vs + rd * 256 + ((sc * 4 + quad) ^ (rd & 7)) * 8);
#pragma unroll
        for (int mt = 0; mt < 2; ++mt)
          oaccT[nt][mt] = __builtin_amdgcn_mfma_f32_16x16x32_f16(vf, pf[mt], oaccT[nt][mt], 0, 0, 0);
      }
      __builtin_amdgcn_s_setprio(0);
    }
    if (kt < 3) {
      __syncthreads();  // all waves done reading Ks/Vs
      const int nx = kt + 1;
#pragma unroll
      for (int c = 0; c < 8; ++c) {
        int idx = c * 256 + tid;
        int row = idx >> 3, sck = idx & 7;
        int dg = sck ^ (row & 7);
        gl_lds16(QK + (size_t)(n * 1024 + nx * 256 + row) * 1024 + 512 + h * 64 + dg * 8,
                 Ks + idx * 8);
        int d = idx >> 5, scv = idx & 31;
        int vg = scv ^ (d & 7);
        gl_lds16(Vt + (size_t)((n * 8 + h) * 64 + d) * 1024 + nx * 256 + vg * 8,
                 Vs + idx * 8);
      }
      __syncthreads();  // drain next tile
    }
  }
  // epilogue: O^T layout — lane owns q = q0 + w*32 + mt*16 + l15, d = nt*16+quad*4+r.
#pragma unroll
  for (int mt = 0; mt < 2; ++mt) {
    int r3 = l15 & 3;
    float lv = lsum[mt][0];
    lv = (r3 == 1) ? lsum[mt][1] : lv;
    lv = (r3 == 2) ? lsum[mt][2] : lv;
    lv = (r3 == 3) ? lsum[mt][3] : lv;
    float lq = __shfl(lv, (l15 >> 2) * 16 + (l15 & 3), 64);
    float rinv = 1.0f / lq;
    int q = q0 + w * 32 + mt * 16 + l15;
    int i = h * 128 + (q >> 3);
    size_t base = (size_t)(n * 1024 + i) * 512 + (q & 7) * 64 + quad * 4;
#pragma unroll
    for (int nt = 0; nt < 4; ++nt) {
      f16x4 pk;
#pragma unroll
      for (int r = 0; r < 4; ++r) pk[r] = (_Float16)(oaccT[nt][mt][r] * rinv);
      *(f16x4*)(O16 + base + nt * 16) = pk;
    }
  }
}

// ---------------- out GEMM: (8192x512)*(512x512)^T + bo -> fp32 out ----------
// 1-D grid 512: BM=128, BN=64, BK=128 (4 k-iters, 8 barriers, was 16).
// xcd = id&7; bm-tile = xcd*8 + (k&7) (batch = xcd, warm from attn);
// bn-tile = k>>3 (0..7)*64. LDS 32+16=48KB, 2 blocks/CU, 2 waves/SIMD.
__global__ __launch_bounds__(256, 2) void out_gemm(
    const _Float16* __restrict__ A, const _Float16* __restrict__ Bw,
    const float* __restrict__ bias, float* __restrict__ out) {
  __shared__ _Float16 As[128 * 128];
  __shared__ _Float16 Bs[64 * 128];
  const int tid = threadIdx.x;
  const int lane = tid & 63, w = tid >> 6;
  const int quad = lane >> 4, l15 = lane & 15;
  const int id = blockIdx.x;
  const int xcd = id & 7, k = id >> 3;          // k 0..63
  const int bm = (xcd * 8 + (k & 7)) * 128;
  const int bn = (k >> 3) * 64;
  const int wr = (w >> 1) * 64, wc = (w & 1) * 32;
  f32x4 acc[4][2] = {};
  for (int k0 = 0; k0 < 512; k0 += 128) {
    __syncthreads();
#pragma unroll
    for (int c = 0; c < 8; ++c) {   // As: 128 rows x 16 chunks = 2048
      int idx = c * 256 + tid;
      int row = idx >> 4, sc = idx & 15;
      int kg = sc ^ (row & 7);      // XOR in low 3 bits of 16-chunk index
      gl_lds16(A + (size_t)(bm + row) * 512 + k0 + kg * 8, As + idx * 8);
    }
#pragma unroll
    for (int c = 0; c < 4; ++c) {   // Bs: 64 rows x 16 chunks = 1024
      int idx = c * 256 + tid;
      int row = idx >> 4, sc = idx & 15;
      int kg = sc ^ (row & 7);
      gl_lds16(Bw + (size_t)(bn + row) * 512 + k0 + kg * 8, Bs + idx * 8);
    }
    __syncthreads();
#pragma unroll
    for (int kh = 0; kh < 4; ++kh) {
      f16x8 af[4], bf[2];
#pragma unroll
      for (int i = 0; i < 4; ++i) {
        int ra = wr + i * 16 + l15;
        af[i] = *(const f16x8*)(As + ra * 128 + ((kh * 4 + quad) ^ (ra & 7)) * 8);
      }
#pragma unroll
      for (int j = 0; j < 2; ++j) {
        int rb = wc + j * 16 + l15;
        bf[j] = *(const f16x8*)(Bs + rb * 128 + ((kh * 4 + quad) ^ (rb & 7)) * 8);
      }
#pragma unroll
      for (int i = 0; i < 4; ++i)
#pragma unroll
        for (int j = 0; j < 2; ++j)
          acc[i][j] = __builtin_amdgcn_mfma_f32_16x16x32_f16(af[i], bf[j], acc[i][j], 0, 0, 0);
    }
  }
#pragma unroll
  for (int j = 0; j < 2; ++j) {
    int col = bn + wc + j * 16 + l15;
    float bb = bias[col];
#pragma unroll
    for (int i = 0; i < 4; ++i) {
      int rowb = bm + wr + i * 16 + quad * 4;
#pragma unroll
      for (int r = 0; r < 4; ++r)
        out[(size_t)(rowb + r) * 512 + col] = acc[i][j][r] + bb;
    }
  }
}

extern "C" void kernel_launch(void* const* d_in, const int* in_sizes, int n_in,
                              void* d_out, int out_size, void* d_ws, size_t ws_size,
                              hipStream_t stream) {
  const float* x  = (const float*)d_in[0];
  const float* Wq = (const float*)d_in[1];
  const float* bq = (const float*)d_in[2];
  const float* Wk = (const float*)d_in[3];
  const float* bk = (const float*)d_in[4];
  const float* Wv = (const float*)d_in[5];
  const float* bv = (const float*)d_in[6];
  const float* Wo = (const float*)d_in[7];
  const float* bo = (const float*)d_in[8];
  float* out = (float*)d_out;
  char* ws = (char*)d_ws;

  _Float16* xs16   = (_Float16*)(ws);                          // 8 MB (reused as O16)
  _Float16* QK     = (_Float16*)(ws + (8u << 20));             // 16 MB
  _Float16* Vt     = (_Float16*)(ws + (24u << 20));            // 8 MB
  _Float16* Wqkv16 = (_Float16*)(ws + (32u << 20));            // 1.5 MB
  _Float16* Wo16   = (_Float16*)(ws + (32u << 20) + 1572864);  // 0.5 MB
  float*    bqkv   = (float*)   (ws + (32u << 20) + 2097152);  // 6 KB

  hipLaunchKernelGGL(prep, dim3(1280), dim3(256), 0, stream,
                     x, Wq, bq, Wk, bk, Wv, bv, Wo, xs16, Wqkv16, bqkv, Wo16);
  hipLaunchKernelGGL(qkv_gemm, dim3(768), dim3(256), 0, stream,
                     xs16, Wqkv16, bqkv, QK, Vt);
  hipLaunchKernelGGL(attn, dim3(512), dim3(256), 0, stream, QK, Vt, xs16);
  hipLaunchKernelGGL(out_gemm, dim3(512), dim3(256), 0, stream,
                     xs16, Wo16, bo, out);
}